// Round 5
// baseline (488.945 us; speedup 1.0000x reference)
//
#include <hip/hip_runtime.h>
#include <math.h>

// GCN 2-layer forward on MI355X — direct-CSR via global atomics + bf16 gather tables.
// R24: delete the bucket machinery. k_partition+k_csr (74MB ebuf/col round-trip,
// two LDS-atomic sorts, 88KB-LDS 1-block/CU partition) are replaced by:
//   k_count   : deg[dst]++ fire-and-forget global atomics (no return -> no stall)
//   k_node    : dinv + bf16 xsb from deg
//   k_scatter : pos=atomicAdd(&cur[dst]) + nontemporal col[dst*96+pos]=src
// Fixed row capacity RCAP=96 (mean deg 32, 11-sigma headroom) -> no scan, no
// rowinfo; row start is dst*96, length deg[dst]. Gather kernels unchanged
// except implicit rowinfo. Pipeline: k_init -> k_count -> k_node -> k_scatter
// -> k_agg -> k_h -> k_l2.

#define NN 100000
#define NE 3200000
#define RCAP 96                     // col slots per node (fixed-capacity rows)

// bf16 helpers: value stored in 16 bits; fp32 = bits<<16.
__device__ __forceinline__ float bl(unsigned u) { return __uint_as_float(u << 16); }
__device__ __forceinline__ float bh(unsigned u) { return __uint_as_float(u & 0xFFFF0000u); }
__device__ __forceinline__ unsigned rne(float f) {           // fp32 -> bf16 bits (RNE)
    unsigned u = __float_as_uint(f);
    return (u + 0x7FFFu + ((u >> 16) & 1u)) >> 16;
}

typedef int vint4 __attribute__((ext_vector_type(4)));

// ---------------- kernels ----------------

// Zero deg[NN] and cur[NN] (contiguous 2*NN ints).
__global__ void __launch_bounds__(256) k_init(int* __restrict__ degcur) {
    int t = blockIdx.x * 256 + threadIdx.x;
    if (t < 2 * NN) degcur[t] = 0;
}

// Degree histogram: 4 independent fire-and-forget global atomics per thread.
// Grid exactly NE/4/256 = 3125.
__global__ void __launch_bounds__(256) k_count(
        const int* __restrict__ dst, int* __restrict__ deg) {
    int i4 = blockIdx.x * 256 + threadIdx.x;
    const vint4* d4 = (const vint4*)dst;
    vint4 d = d4[i4];
    atomicAdd(&deg[d.x], 1);
    atomicAdd(&deg[d.y], 1);
    atomicAdd(&deg[d.z], 1);
    atomicAdd(&deg[d.w], 1);
}

// Per-node: dinv = rsqrt(deg+1), bf16 xs row = x * dinv (32B).
__global__ void __launch_bounds__(256) k_node(
        const int* __restrict__ deg, const float* __restrict__ x,
        float* __restrict__ dinv, unsigned int* __restrict__ xsb, int N) {
    int node = blockIdx.x * 256 + threadIdx.x;
    if (node >= N) return;
    int v = deg[node];
    float di = rsqrtf((float)(v + 1));  // +1 self loop
    dinv[node] = di;
    const float4* x4 = (const float4*)(x + (size_t)node * 16);
    float4 A = x4[0], B = x4[1], C = x4[2], D = x4[3];
    uint4 o0, o1;
    o0.x = rne(A.x * di) | (rne(A.y * di) << 16);
    o0.y = rne(A.z * di) | (rne(A.w * di) << 16);
    o0.z = rne(B.x * di) | (rne(B.y * di) << 16);
    o0.w = rne(B.z * di) | (rne(B.w * di) << 16);
    o1.x = rne(C.x * di) | (rne(C.y * di) << 16);
    o1.y = rne(C.z * di) | (rne(C.w * di) << 16);
    o1.z = rne(D.x * di) | (rne(D.y * di) << 16);
    o1.w = rne(D.z * di) | (rne(D.w * di) << 16);
    uint4* op = (uint4*)xsb;
    op[(size_t)node * 2 + 0] = o0;
    op[(size_t)node * 2 + 1] = o1;
}

// Scatter: pos = atomicAdd(&cur[dst],1) (4 independent, latency hidden by max
// occupancy), nontemporal store col[dst*96+pos] = src (bypass L2 allocate to
// limit cross-XCD partial-line bouncing). Grid 3125.
__global__ void __launch_bounds__(256) k_scatter(
        const int* __restrict__ src, const int* __restrict__ dst,
        int* __restrict__ cur, int* __restrict__ col) {
    int i4 = blockIdx.x * 256 + threadIdx.x;
    const vint4* s4 = (const vint4*)src;
    const vint4* d4 = (const vint4*)dst;
    vint4 s = s4[i4], d = d4[i4];
    int p;
    p = atomicAdd(&cur[d.x], 1);
    if (p < RCAP) __builtin_nontemporal_store(s.x, &col[d.x * RCAP + p]);
    p = atomicAdd(&cur[d.y], 1);
    if (p < RCAP) __builtin_nontemporal_store(s.y, &col[d.y * RCAP + p]);
    p = atomicAdd(&cur[d.z], 1);
    if (p < RCAP) __builtin_nontemporal_store(s.z, &col[d.z * RCAP + p]);
    p = atomicAdd(&cur[d.w], 1);
    if (p < RCAP) __builtin_nontemporal_store(s.w, &col[d.w * RCAP + p]);
}

// Aggregation: FOUR nodes per wave (quarter-wave each), 8 edge slots x 2 chunk
// lanes, uint4 (16B) bf16 gathers, 3-level fold, + self, write agg16 row bf16.
// Row start = wid*RCAP, length deg[wid].
__global__ void __launch_bounds__(256) k_agg(
        const int* __restrict__ deg, const int* __restrict__ col,
        const unsigned int* __restrict__ xsb, unsigned int* __restrict__ aggb,
        int N) {
    int wv = (int)((blockIdx.x * 256 + threadIdx.x) >> 6);
    int lane = threadIdx.x & 63;
    int q = lane >> 4;                 // quarter 0..3 -> node
    int wid = wv * 4 + q;
    if (wid >= N) return;              // quarter-wave-uniform
    int lq = lane & 15;
    int r = lq >> 1, c = lq & 1;       // edge slot 0..7, chunk 0..1 (16B)
    int beg = wid * RCAP;
    int end = beg + deg[wid];
    const uint4* xb = (const uint4*)xsb;   // row i = xb[i*2 + c]
    float a0 = 0.f, a1 = 0.f, a2 = 0.f, a3 = 0.f;   // features 8c..8c+7
    float a4 = 0.f, a5 = 0.f, a6 = 0.f, a7 = 0.f;
    int j = beg + r;
    while (j + 8 < end) {   // 2 edges per lane in flight (16/wave-quarter)
        int s0 = col[j], s1 = col[j + 8];
        uint4 q0 = xb[(size_t)s0 * 2 + c];
        uint4 q1 = xb[(size_t)s1 * 2 + c];
        a0 += bl(q0.x); a1 += bh(q0.x); a2 += bl(q0.y); a3 += bh(q0.y);
        a4 += bl(q0.z); a5 += bh(q0.z); a6 += bl(q0.w); a7 += bh(q0.w);
        a0 += bl(q1.x); a1 += bh(q1.x); a2 += bl(q1.y); a3 += bh(q1.y);
        a4 += bl(q1.z); a5 += bh(q1.z); a6 += bl(q1.w); a7 += bh(q1.w);
        j += 16;
    }
    if (j < end) {
        int s = col[j];
        uint4 qq = xb[(size_t)s * 2 + c];
        a0 += bl(qq.x); a1 += bh(qq.x); a2 += bl(qq.y); a3 += bh(qq.y);
        a4 += bl(qq.z); a5 += bh(qq.z); a6 += bl(qq.w); a7 += bh(qq.w);
    }
    // fold 8 edge slots -> lanes lq 0..1 of each quarter (chunk c preserved)
#pragma unroll
    for (int off = 8; off >= 2; off >>= 1) {
        a0 += __shfl_down(a0, off);
        a1 += __shfl_down(a1, off);
        a2 += __shfl_down(a2, off);
        a3 += __shfl_down(a3, off);
        a4 += __shfl_down(a4, off);
        a5 += __shfl_down(a5, off);
        a6 += __shfl_down(a6, off);
        a7 += __shfl_down(a7, off);
    }
    if (lq < 2) {  // self term + write (chunk c == lq)
        uint4 qq = xb[(size_t)wid * 2 + lq];
        a0 += bl(qq.x); a1 += bh(qq.x); a2 += bl(qq.y); a3 += bh(qq.y);
        a4 += bl(qq.z); a5 += bh(qq.z); a6 += bl(qq.w); a7 += bh(qq.w);
        uint4 o;
        o.x = rne(a0) | (rne(a1) << 16);
        o.y = rne(a2) | (rne(a3) << 16);
        o.z = rne(a4) | (rne(a5) << 16);
        o.w = rne(a6) | (rne(a7) << 16);
        ((uint4*)aggb)[(size_t)wid * 2 + lq] = o;
    }
}

// Dense per-node epilogue: h = agg16 @ W1, z = relu(dinv*h + b1),
// p = z @ W2, g2 = p*dinv (bf16x4). One thread per node, zero shuffles.
__global__ void __launch_bounds__(256) k_h(
        const unsigned int* __restrict__ aggb, const float* __restrict__ dinv,
        const float* __restrict__ W1, const float* __restrict__ b1,
        const float* __restrict__ W2, unsigned int* __restrict__ g2b, int N) {
    __shared__ float W1s[16 * 32];
    __shared__ float W2s[96];
    __shared__ float b1s[32];
    for (int t = threadIdx.x; t < 512; t += 256) W1s[t] = W1[t];
    if (threadIdx.x < 96) W2s[threadIdx.x] = W2[threadIdx.x];
    if (threadIdx.x < 32) b1s[threadIdx.x] = b1[threadIdx.x];
    __syncthreads();
    int i = blockIdx.x * 256 + threadIdx.x;
    if (i >= N) return;
    const uint4* ab = (const uint4*)aggb;
    uint4 q0 = ab[(size_t)i * 2 + 0];
    uint4 q1 = ab[(size_t)i * 2 + 1];
    float a[16] = {bl(q0.x), bh(q0.x), bl(q0.y), bh(q0.y),
                   bl(q0.z), bh(q0.z), bl(q0.w), bh(q0.w),
                   bl(q1.x), bh(q1.x), bl(q1.y), bh(q1.y),
                   bl(q1.z), bh(q1.z), bl(q1.w), bh(q1.w)};
    float di = dinv[i];
    float p0 = 0.f, p1 = 0.f, p2 = 0.f;
#pragma unroll
    for (int jj = 0; jj < 32; jj++) {
        float o = 0.f;
#pragma unroll
        for (int k = 0; k < 16; k++) o = fmaf(a[k], W1s[k * 32 + jj], o);
        float z = fmaxf(fmaf(di, o, b1s[jj]), 0.f);
        p0 = fmaf(z, W2s[jj * 3 + 0], p0);
        p1 = fmaf(z, W2s[jj * 3 + 1], p1);
        p2 = fmaf(z, W2s[jj * 3 + 2], p2);
    }
    uint2 o;
    o.x = rne(p0 * di) | (rne(p1 * di) << 16);
    o.y = rne(p2 * di);
    ((uint2*)g2b)[i] = o;
}

// Layer-2: EIGHT nodes per wave (8 lanes each), 8B bf16 g2 gathers, unroll x2,
// 3-level shuffle reduce, + self + bias, log_softmax. Row start = wid*RCAP.
__global__ void __launch_bounds__(256) k_l2(
        const int* __restrict__ deg, const int* __restrict__ col,
        const unsigned int* __restrict__ g2b, const float* __restrict__ dinv,
        const float* __restrict__ b2, float* __restrict__ out, int N) {
    int wid = (int)((blockIdx.x * 256 + threadIdx.x) >> 3);  // node per 8 lanes
    if (wid >= N) return;
    int lo = threadIdx.x & 7;
    int beg = wid * RCAP;
    int end = beg + deg[wid];
    const uint2* gb = (const uint2*)g2b;
    float a0 = 0.f, a1 = 0.f, a2 = 0.f;
    int j = beg + lo;
    while (j + 8 < end) {   // 2 edges in flight
        uint2 v0 = gb[col[j]];
        uint2 v1 = gb[col[j + 8]];
        a0 += bl(v0.x); a1 += bh(v0.x); a2 += bl(v0.y);
        a0 += bl(v1.x); a1 += bh(v1.x); a2 += bl(v1.y);
        j += 16;
    }
    if (j < end) {
        uint2 v = gb[col[j]];
        a0 += bl(v.x); a1 += bh(v.x); a2 += bl(v.y);
    }
#pragma unroll
    for (int off = 4; off >= 1; off >>= 1) {
        a0 += __shfl_down(a0, off);
        a1 += __shfl_down(a1, off);
        a2 += __shfl_down(a2, off);
    }
    if (lo == 0) {
        float di = dinv[wid];
        uint2 sv = gb[wid];
        float v0 = fmaf(di, a0 + bl(sv.x), b2[0]);
        float v1 = fmaf(di, a1 + bh(sv.x), b2[1]);
        float v2 = fmaf(di, a2 + bl(sv.y), b2[2]);
        float m = fmaxf(v0, fmaxf(v1, v2));
        float lse = m + logf(expf(v0 - m) + expf(v1 - m) + expf(v2 - m));
        out[(size_t)wid * 3 + 0] = v0 - lse;
        out[(size_t)wid * 3 + 1] = v1 - lse;
        out[(size_t)wid * 3 + 2] = v2 - lse;
    }
}

// ---------------- launch ----------------

extern "C" void kernel_launch(void* const* d_in, const int* in_sizes, int n_in,
                              void* d_out, int out_size, void* d_ws, size_t ws_size,
                              hipStream_t stream) {
    const float* x  = (const float*)d_in[0];
    const int*   ei = (const int*)d_in[1];   // [2, E] int32
    const float* W1 = (const float*)d_in[2];
    const float* b1 = (const float*)d_in[3];
    const float* W2 = (const float*)d_in[4];
    const float* b2 = (const float*)d_in[5];
    float* out = (float*)d_out;

    const int* src = ei;
    const int* dst = ei + NE;

    // ws (4B units), no aliasing:
    // col[NN*RCAP] | xsb[NN*8] | aggb[NN*8] | g2b[NN*2] | dinv[NN]
    // | deg[NN] | cur[NN]                     (~47 MB)
    int*          col  = (int*)d_ws;
    unsigned int* xsb  = (unsigned int*)(col + (size_t)NN * RCAP);
    unsigned int* aggb = xsb + (size_t)NN * 8;
    unsigned int* g2b  = aggb + (size_t)NN * 8;
    float*        dinv = (float*)(g2b + (size_t)NN * 2);
    int*          deg  = (int*)(dinv + NN);
    int*          cur  = deg + NN;           // contiguous with deg for k_init

    const int B = 256;
    int gbI = (2 * NN + B - 1) / B;    // 782
    int gbE = NE / 4 / B;              // 3125 exact
    int gbN = (NN + B - 1) / B;        // 391
    int gbW1 = (NN * 16 + B - 1) / B;  // 6250, quarter-wave per node
    int gbW2 = (NN * 8 + B - 1) / B;   // 3125, 8 lanes per node

    k_init<<<gbI, B, 0, stream>>>(deg);
    k_count<<<gbE, B, 0, stream>>>(dst, deg);
    k_node<<<gbN, B, 0, stream>>>(deg, x, dinv, xsb, NN);
    k_scatter<<<gbE, B, 0, stream>>>(src, dst, cur, col);
    k_agg<<<gbW1, B, 0, stream>>>(deg, col, xsb, aggb, NN);
    k_h<<<gbN, B, 0, stream>>>(aggb, dinv, W1, b1, W2, g2b, NN);
    k_l2<<<gbW2, B, 0, stream>>>(deg, col, g2b, dinv, b2, out, NN);
}

// Round 6
// 93.868 us; speedup vs baseline: 5.2089x; 5.2089x over previous
//
#include <hip/hip_runtime.h>
#include <math.h>

// GCN 2-layer forward on MI355X — fixed-capacity bucket CSR + bf16 gather tables.
// R25: revert R24's global-scatter CSR (k_scatter was 300us: every 4B nt store
// became a 64B HBM line write, WRITE_SIZE 195MB). Back to R23's bucket pipeline
// (95.3us) with k_partition at 1024 threads/block: same 256 blocks / 88KB LDS /
// 16-edge bursts, but 16 waves/CU instead of 8 (occupancy was the weakest in
// the pipeline at 25%), and the 782-bucket scan collapses to ONE phase
// (782 <= 1024), removing two barriers. Zero traffic change.

#define NN 100000
#define NE 3200000
#define BSH 7
#define NPB 128                     // nodes per bucket
#define NB  ((NN + NPB - 1) / NPB)  // 782
#define EPB 12544                   // edges per partition block -> 256 blocks
#define CAP 6144                    // slots per bucket region (mean 4096, sigma~64)
#define SCAP 5120                   // LDS staging capacity in k_csr (16 sigma)

// bf16 helpers: value stored in 16 bits; fp32 = bits<<16.
__device__ __forceinline__ float bl(unsigned u) { return __uint_as_float(u << 16); }
__device__ __forceinline__ float bh(unsigned u) { return __uint_as_float(u & 0xFFFF0000u); }
__device__ __forceinline__ unsigned rne(float f) {           // fp32 -> bf16 bits (RNE)
    unsigned u = __float_as_uint(f);
    return (u + 0x7FFFu + ((u >> 16) & 1u)) >> 16;
}

typedef int vint4 __attribute__((ext_vector_type(4)));

// ---------------- kernels ----------------

// Zero the 782 bucket counters (runtime fillBuffer was ~2x slower).
__global__ void __launch_bounds__(256) k_zero(int* __restrict__ bcur) {
    int t = blockIdx.x * 256 + threadIdx.x;
    if (t < NB) bcur[t] = 0;
}

// LDS-staged partition: reg-cached dst (4x int4) -> block hist over 782 buckets
// (single-phase 1024-thread scan) -> global reserve (b*CAP + atomicAdd on
// zeroed bcur) -> LDS bucket-sort (sebuf+sbkt) -> coalesced burst copy-out.
// 256 blocks x 1024 threads = 1 block/CU, 16 waves/CU, ~88KB LDS.
__global__ void __launch_bounds__(1024) k_partition(
        const int* __restrict__ src, const int* __restrict__ dst,
        int* __restrict__ bcur, unsigned int* __restrict__ ebuf, int E) {
    __shared__ int hist[NB];
    __shared__ int lbase[NB];
    __shared__ int gbase[NB];
    __shared__ int lcur[NB];
    __shared__ unsigned int sebuf[EPB];
    __shared__ unsigned short sbkt[EPB];
    __shared__ int wsum[16];
    int tid = threadIdx.x;
    int e0 = blockIdx.x * EPB;
    int e1 = min(e0 + EPB, E);
    int cnt = e1 - e0;                 // multiple of 4 (tail = 1280)
    int cnt4 = cnt >> 2;
    if (tid < NB) { hist[tid] = 0; lcur[tid] = 0; }
    __syncthreads();
    const vint4* d4 = (const vint4*)(dst + e0);
    vint4 dc[4];
#pragma unroll
    for (int r = 0; r < 4; r++) {
        int i4 = r * 1024 + tid;
        if (i4 < cnt4) {
            dc[r] = d4[i4];
            atomicAdd(&hist[dc[r].x >> BSH], 1);
            atomicAdd(&hist[dc[r].y >> BSH], 1);
            atomicAdd(&hist[dc[r].z >> BSH], 1);
            atomicAdd(&hist[dc[r].w >> BSH], 1);
        }
    }
    __syncthreads();
    int lane = tid & 63, w = tid >> 6;
    // ---- single-phase scan over all 782 buckets (1024 threads, v=0 beyond) ----
    {
        int v = (tid < NB) ? hist[tid] : 0;
        int incl = v;
#pragma unroll
        for (int off = 1; off < 64; off <<= 1) {
            int u = __shfl_up(incl, off);
            if (lane >= off) incl += u;
        }
        if (lane == 63) wsum[w] = incl;
        __syncthreads();
        int woff = 0;
#pragma unroll
        for (int k = 0; k < 16; k++) woff += (k < w) ? wsum[k] : 0;
        int excl = incl - v + woff;
        if (tid < NB) {
            lbase[tid] = excl;
            gbase[tid] = tid * CAP + (v ? atomicAdd(&bcur[tid], v) : 0);
        }
        __syncthreads();
    }
    // ---- scatter into LDS, bucket-sorted (dst from regs, src fresh int4) ----
    const vint4* s4 = (const vint4*)(src + e0);
#pragma unroll
    for (int r = 0; r < 4; r++) {
        int i4 = r * 1024 + tid;
        if (i4 < cnt4) {
            vint4 sv = s4[i4];
            int d, b, p;
            d = dc[r].x; b = d >> BSH; p = lbase[b] + atomicAdd(&lcur[b], 1);
            sebuf[p] = (unsigned)sv.x | ((unsigned)(d & (NPB - 1)) << 20);
            sbkt[p] = (unsigned short)b;
            d = dc[r].y; b = d >> BSH; p = lbase[b] + atomicAdd(&lcur[b], 1);
            sebuf[p] = (unsigned)sv.y | ((unsigned)(d & (NPB - 1)) << 20);
            sbkt[p] = (unsigned short)b;
            d = dc[r].z; b = d >> BSH; p = lbase[b] + atomicAdd(&lcur[b], 1);
            sebuf[p] = (unsigned)sv.z | ((unsigned)(d & (NPB - 1)) << 20);
            sbkt[p] = (unsigned short)b;
            d = dc[r].w; b = d >> BSH; p = lbase[b] + atomicAdd(&lcur[b], 1);
            sebuf[p] = (unsigned)sv.w | ((unsigned)(d & (NPB - 1)) << 20);
            sbkt[p] = (unsigned short)b;
        }
    }
    __syncthreads();
    // ---- burst copy-out: consecutive lanes -> consecutive ebuf positions ----
    for (int p = tid; p < cnt; p += 1024) {
        int b = sbkt[p];
        ebuf[gbase[b] + (p - lbase[b])] = sebuf[p];
    }
}

// per-bucket counting sort by dstLocal -> col, bucket staged in LDS (single nt
// ebuf read; scatter from LDS, regular col stores). Emits rowinfo(pos<<8|deg),
// dinv, bf16 xs row. 782 blocks x 256 threads (~3/CU), ~22KB LDS.
__global__ void __launch_bounds__(256) k_csr(
        const unsigned int* __restrict__ ebuf, const int* __restrict__ bcur,
        const float* __restrict__ x, int* __restrict__ col,
        unsigned int* __restrict__ rowinfo, float* __restrict__ dinv,
        unsigned int* __restrict__ xsb, int N) {
    __shared__ unsigned int se[SCAP];
    __shared__ int hist[NPB];
    __shared__ int base[NPB];
    __shared__ int lcur[NPB];
    __shared__ int wsum[4];
    int b = blockIdx.x;
    int tid = threadIdx.x;
    int beg = b * CAP;
    int cnt = bcur[b];               // count (bcur zero-initialized)
    int cl = min(cnt, SCAP);
    if (tid < NPB) { hist[tid] = 0; lcur[tid] = 0; }
    __syncthreads();
    for (int j = tid; j < cl; j += 256) {
        unsigned pe = __builtin_nontemporal_load(&ebuf[beg + j]);
        se[j] = pe;
        atomicAdd(&hist[pe >> 20], 1);
    }
    for (int j = SCAP + tid; j < cnt; j += 256)          // overflow path (~never)
        atomicAdd(&hist[ebuf[beg + j] >> 20], 1);
    __syncthreads();
    int lane = tid & 63, w = tid >> 6;
    int v = (tid < NPB) ? hist[tid] : 0;
    int incl = v;
#pragma unroll
    for (int off = 1; off < 64; off <<= 1) {
        int u = __shfl_up(incl, off);
        if (lane >= off) incl += u;
    }
    if (lane == 63) wsum[w] = incl;
    __syncthreads();
    int woff = 0;
#pragma unroll
    for (int k = 0; k < 4; k++) woff += (k < w) ? wsum[k] : 0;
    int excl = incl - v + woff;
    int node = b * NPB + tid;
    if (tid < NPB) {
        base[tid] = excl;
        if (node < N) {
            float di = rsqrtf((float)(v + 1));  // +1 self loop
            dinv[node] = di;
            rowinfo[node] = ((unsigned)(beg + excl) << 8) | (unsigned)v;  // deg<256
            const float4* x4 = (const float4*)(x + (size_t)node * 16);
            float4 A = x4[0], B = x4[1], C = x4[2], D = x4[3];
            uint4 o0, o1;
            o0.x = rne(A.x * di) | (rne(A.y * di) << 16);
            o0.y = rne(A.z * di) | (rne(A.w * di) << 16);
            o0.z = rne(B.x * di) | (rne(B.y * di) << 16);
            o0.w = rne(B.z * di) | (rne(B.w * di) << 16);
            o1.x = rne(C.x * di) | (rne(C.y * di) << 16);
            o1.y = rne(C.z * di) | (rne(C.w * di) << 16);
            o1.z = rne(D.x * di) | (rne(D.y * di) << 16);
            o1.w = rne(D.z * di) | (rne(D.w * di) << 16);
            uint4* op = (uint4*)xsb;
            op[(size_t)node * 2 + 0] = o0;
            op[(size_t)node * 2 + 1] = o1;
        }
    }
    __syncthreads();
    for (int j = tid; j < cl; j += 256) {
        unsigned pe = se[j];
        int dl = pe >> 20;
        int pos = beg + base[dl] + atomicAdd(&lcur[dl], 1);
        col[pos] = (int)(pe & 0xFFFFF);
    }
    for (int j = SCAP + tid; j < cnt; j += 256) {        // overflow path (~never)
        unsigned pe = ebuf[beg + j];
        int dl = pe >> 20;
        int pos = beg + base[dl] + atomicAdd(&lcur[dl], 1);
        col[pos] = (int)(pe & 0xFFFFF);
    }
}

// Aggregation: FOUR nodes per wave (quarter-wave each), 8 edge slots x 2 chunk
// lanes, uint4 (16B) bf16 gathers, 3-level fold, + self, write agg16 row bf16.
__global__ void __launch_bounds__(256) k_agg(
        const unsigned int* __restrict__ rowinfo, const int* __restrict__ col,
        const unsigned int* __restrict__ xsb, unsigned int* __restrict__ aggb,
        int N) {
    int wv = (int)((blockIdx.x * 256 + threadIdx.x) >> 6);
    int lane = threadIdx.x & 63;
    int q = lane >> 4;                 // quarter 0..3 -> node
    int wid = wv * 4 + q;
    if (wid >= N) return;              // quarter-wave-uniform
    int lq = lane & 15;
    int r = lq >> 1, c = lq & 1;       // edge slot 0..7, chunk 0..1 (16B)
    unsigned info = rowinfo[wid];
    int beg = (int)(info >> 8);
    int end = beg + (int)(info & 255u);
    const uint4* xb = (const uint4*)xsb;   // row i = xb[i*2 + c]
    float a0 = 0.f, a1 = 0.f, a2 = 0.f, a3 = 0.f;   // features 8c..8c+7
    float a4 = 0.f, a5 = 0.f, a6 = 0.f, a7 = 0.f;
    int j = beg + r;
    while (j + 8 < end) {   // 2 edges per lane in flight (16/wave-quarter)
        int s0 = col[j], s1 = col[j + 8];
        uint4 q0 = xb[(size_t)s0 * 2 + c];
        uint4 q1 = xb[(size_t)s1 * 2 + c];
        a0 += bl(q0.x); a1 += bh(q0.x); a2 += bl(q0.y); a3 += bh(q0.y);
        a4 += bl(q0.z); a5 += bh(q0.z); a6 += bl(q0.w); a7 += bh(q0.w);
        a0 += bl(q1.x); a1 += bh(q1.x); a2 += bl(q1.y); a3 += bh(q1.y);
        a4 += bl(q1.z); a5 += bh(q1.z); a6 += bl(q1.w); a7 += bh(q1.w);
        j += 16;
    }
    if (j < end) {
        int s = col[j];
        uint4 qq = xb[(size_t)s * 2 + c];
        a0 += bl(qq.x); a1 += bh(qq.x); a2 += bl(qq.y); a3 += bh(qq.y);
        a4 += bl(qq.z); a5 += bh(qq.z); a6 += bl(qq.w); a7 += bh(qq.w);
    }
    // fold 8 edge slots -> lanes lq 0..1 of each quarter (chunk c preserved)
#pragma unroll
    for (int off = 8; off >= 2; off >>= 1) {
        a0 += __shfl_down(a0, off);
        a1 += __shfl_down(a1, off);
        a2 += __shfl_down(a2, off);
        a3 += __shfl_down(a3, off);
        a4 += __shfl_down(a4, off);
        a5 += __shfl_down(a5, off);
        a6 += __shfl_down(a6, off);
        a7 += __shfl_down(a7, off);
    }
    if (lq < 2) {  // self term + write (chunk c == lq)
        uint4 qq = xb[(size_t)wid * 2 + lq];
        a0 += bl(qq.x); a1 += bh(qq.x); a2 += bl(qq.y); a3 += bh(qq.y);
        a4 += bl(qq.z); a5 += bh(qq.z); a6 += bl(qq.w); a7 += bh(qq.w);
        uint4 o;
        o.x = rne(a0) | (rne(a1) << 16);
        o.y = rne(a2) | (rne(a3) << 16);
        o.z = rne(a4) | (rne(a5) << 16);
        o.w = rne(a6) | (rne(a7) << 16);
        ((uint4*)aggb)[(size_t)wid * 2 + lq] = o;
    }
}

// Dense per-node epilogue: h = agg16 @ W1, z = relu(dinv*h + b1),
// p = z @ W2, g2 = p*dinv (bf16x4). One thread per node, zero shuffles.
__global__ void __launch_bounds__(256) k_h(
        const unsigned int* __restrict__ aggb, const float* __restrict__ dinv,
        const float* __restrict__ W1, const float* __restrict__ b1,
        const float* __restrict__ W2, unsigned int* __restrict__ g2b, int N) {
    __shared__ float W1s[16 * 32];
    __shared__ float W2s[96];
    __shared__ float b1s[32];
    for (int t = threadIdx.x; t < 512; t += 256) W1s[t] = W1[t];
    if (threadIdx.x < 96) W2s[threadIdx.x] = W2[threadIdx.x];
    if (threadIdx.x < 32) b1s[threadIdx.x] = b1[threadIdx.x];
    __syncthreads();
    int i = blockIdx.x * 256 + threadIdx.x;
    if (i >= N) return;
    const uint4* ab = (const uint4*)aggb;
    uint4 q0 = ab[(size_t)i * 2 + 0];
    uint4 q1 = ab[(size_t)i * 2 + 1];
    float a[16] = {bl(q0.x), bh(q0.x), bl(q0.y), bh(q0.y),
                   bl(q0.z), bh(q0.z), bl(q0.w), bh(q0.w),
                   bl(q1.x), bh(q1.x), bl(q1.y), bh(q1.y),
                   bl(q1.z), bh(q1.z), bl(q1.w), bh(q1.w)};
    float di = dinv[i];
    float p0 = 0.f, p1 = 0.f, p2 = 0.f;
#pragma unroll
    for (int jj = 0; jj < 32; jj++) {
        float o = 0.f;
#pragma unroll
        for (int k = 0; k < 16; k++) o = fmaf(a[k], W1s[k * 32 + jj], o);
        float z = fmaxf(fmaf(di, o, b1s[jj]), 0.f);
        p0 = fmaf(z, W2s[jj * 3 + 0], p0);
        p1 = fmaf(z, W2s[jj * 3 + 1], p1);
        p2 = fmaf(z, W2s[jj * 3 + 2], p2);
    }
    uint2 o;
    o.x = rne(p0 * di) | (rne(p1 * di) << 16);
    o.y = rne(p2 * di);
    ((uint2*)g2b)[i] = o;
}

// Layer-2: EIGHT nodes per wave (8 lanes each), 8B bf16 g2 gathers, unroll x2,
// 3-level shuffle reduce, + self + bias, log_softmax.
__global__ void __launch_bounds__(256) k_l2(
        const unsigned int* __restrict__ rowinfo, const int* __restrict__ col,
        const unsigned int* __restrict__ g2b, const float* __restrict__ dinv,
        const float* __restrict__ b2, float* __restrict__ out, int N) {
    int wid = (int)((blockIdx.x * 256 + threadIdx.x) >> 3);  // node per 8 lanes
    if (wid >= N) return;
    int lo = threadIdx.x & 7;
    unsigned info = rowinfo[wid];
    int beg = (int)(info >> 8);
    int end = beg + (int)(info & 255u);
    const uint2* gb = (const uint2*)g2b;
    float a0 = 0.f, a1 = 0.f, a2 = 0.f;
    int j = beg + lo;
    while (j + 8 < end) {   // 2 edges in flight
        uint2 v0 = gb[col[j]];
        uint2 v1 = gb[col[j + 8]];
        a0 += bl(v0.x); a1 += bh(v0.x); a2 += bl(v0.y);
        a0 += bl(v1.x); a1 += bh(v1.x); a2 += bl(v1.y);
        j += 16;
    }
    if (j < end) {
        uint2 v = gb[col[j]];
        a0 += bl(v.x); a1 += bh(v.x); a2 += bl(v.y);
    }
#pragma unroll
    for (int off = 4; off >= 1; off >>= 1) {
        a0 += __shfl_down(a0, off);
        a1 += __shfl_down(a1, off);
        a2 += __shfl_down(a2, off);
    }
    if (lo == 0) {
        float di = dinv[wid];
        uint2 sv = gb[wid];
        float v0 = fmaf(di, a0 + bl(sv.x), b2[0]);
        float v1 = fmaf(di, a1 + bh(sv.x), b2[1]);
        float v2 = fmaf(di, a2 + bl(sv.y), b2[2]);
        float m = fmaxf(v0, fmaxf(v1, v2));
        float lse = m + logf(expf(v0 - m) + expf(v1 - m) + expf(v2 - m));
        out[(size_t)wid * 3 + 0] = v0 - lse;
        out[(size_t)wid * 3 + 1] = v1 - lse;
        out[(size_t)wid * 3 + 2] = v2 - lse;
    }
}

// ---------------- launch ----------------

extern "C" void kernel_launch(void* const* d_in, const int* in_sizes, int n_in,
                              void* d_out, int out_size, void* d_ws, size_t ws_size,
                              hipStream_t stream) {
    const float* x  = (const float*)d_in[0];
    const int*   ei = (const int*)d_in[1];   // [2, E] int32
    const float* W1 = (const float*)d_in[2];
    const float* b1 = (const float*)d_in[3];
    const float* W2 = (const float*)d_in[4];
    const float* b2 = (const float*)d_in[5];
    float* out = (float*)d_out;

    const int* src = ei;
    const int* dst = ei + NE;

    // ws (4B units), no aliasing:
    // ebuf[NB*CAP] | col[NB*CAP] | xsb[NN*8] | aggb[NN*8] | g2b[NN*2]
    // | dinv[NN] | rowinfo[NN] | bcur[NB]        (~55 MB)
    unsigned int* ebuf = (unsigned int*)d_ws;
    int*          col  = (int*)(ebuf + (size_t)NB * CAP);
    unsigned int* xsb  = (unsigned int*)(col + (size_t)NB * CAP);
    unsigned int* aggb = xsb + (size_t)NN * 8;
    unsigned int* g2b  = aggb + (size_t)NN * 8;
    float*        dinv = (float*)(g2b + (size_t)NN * 2);
    unsigned int* rowinfo = (unsigned int*)(dinv + NN);
    int*          bcur = (int*)(rowinfo + NN);

    const int B = 256;
    int gbP = (NE + EPB - 1) / EPB;    // 256
    int gbS = (NN + B - 1) / B;
    int gbW1 = (NN * 16 + B - 1) / B;  // quarter-wave per node
    int gbW2 = (NN * 8 + B - 1) / B;   // 8 lanes per node
    int gbZ = (NB + B - 1) / B;        // 4

    k_zero<<<gbZ, B, 0, stream>>>(bcur);
    k_partition<<<gbP, 1024, 0, stream>>>(src, dst, bcur, ebuf, NE);
    k_csr<<<NB, B, 0, stream>>>(ebuf, bcur, x, col, rowinfo, dinv, xsb, NN);
    k_agg<<<gbW1, B, 0, stream>>>(rowinfo, col, xsb, aggb, NN);
    k_h<<<gbS, B, 0, stream>>>(aggb, dinv, W1, b1, W2, g2b, NN);
    k_l2<<<gbW2, B, 0, stream>>>(rowinfo, col, g2b, dinv, b2, out, NN);
}